// Round 1
// baseline (237.641 us; speedup 1.0000x reference)
//
#include <hip/hip_runtime.h>
#include <stdint.h>

typedef __bf16 bf16x8 __attribute__((ext_vector_type(8)));
typedef __bf16 bf16x4 __attribute__((ext_vector_type(4)));
typedef float  f32x4  __attribute__((ext_vector_type(4)));

#define NB   32
#define CI   128
#define HH   56
#define WW   56
#define CO   256
#define HP   58          // 56 + 2 halo
#define HW   (HH*WW)     // 3136
#define MTOT (NB*HW)     // 100352
#define KTOT 1152        // 9*128, k = (r*3+s)*128 + c

#define XT_ELEMS ((size_t)NB*HP*HP*CI)   // 13,778,944
#define XT_BYTES (XT_ELEMS*2)            // 27,557,888 (16B-aligned)

// ---------- zero-fill padded x_t (halo must be 0) ----------
__global__ void zero_kernel(int4* __restrict__ p, int n16) {
  int i = blockIdx.x * blockDim.x + threadIdx.x;
  if (i < n16) p[i] = make_int4(0, 0, 0, 0);
}

// ---------- x: NCHW f32 -> padded NHWC bf16 (LDS transpose per (n,h)) ----------
__global__ void xpose_kernel(const float* __restrict__ x, __bf16* __restrict__ xt) {
  int nh = blockIdx.x;
  int n = nh / HH, h = nh % HH;
  __shared__ float tile[CI * 57];        // +1 pad breaks bank conflicts
  const float* src = x + (size_t)n * CI * HW + (size_t)h * WW;
  int t = threadIdx.x;
  for (int idx = t; idx < CI * WW; idx += 256) {
    int c = idx / WW, w = idx - c * WW;
    tile[c * 57 + w] = src[(size_t)c * HW + w];   // coalesced along w
  }
  __syncthreads();
  __bf16* dst = xt + ((size_t)(n * HP + h + 1) * HP + 1) * CI;
  for (int idx = t; idx < WW * 32; idx += 256) {
    int w = idx >> 5, c4 = (idx & 31) * 4;
    bf16x4 v;
    v[0] = (__bf16)tile[(c4 + 0) * 57 + w];
    v[1] = (__bf16)tile[(c4 + 1) * 57 + w];
    v[2] = (__bf16)tile[(c4 + 2) * 57 + w];
    v[3] = (__bf16)tile[(c4 + 3) * 57 + w];
    *(bf16x4*)(dst + (size_t)w * CI + c4) = v;    // contiguous along c
  }
}

// ---------- weight: OIHW f32 -> [CO][KTOT] bf16, k=(r*3+s)*128+c ----------
__global__ void wxform_kernel(const float* __restrict__ wg, __bf16* __restrict__ wt) {
  int id = blockIdx.x * 256 + threadIdx.x;   // CO*KTOT = 294912 total
  int o = id / KTOT;
  int k = id - o * KTOT;
  int rs = k >> 7, c = k & 127;
  wt[id] = (__bf16)wg[(size_t)o * KTOT + c * 9 + rs];
}

// ---------- implicit-GEMM conv: m97 structure ----------
#define BM 128
#define BN 128
#define BK 32

__device__ __forceinline__ void gload_lds16(const __bf16* g, __bf16* l) {
  __builtin_amdgcn_global_load_lds(
      (const __attribute__((address_space(1))) void*)g,
      (__attribute__((address_space(3))) void*)l, 16, 0, 0);
}

__global__ __launch_bounds__(256) void conv_gemm(
    const __bf16* __restrict__ xt, const __bf16* __restrict__ wt,
    const float* __restrict__ bias, float* __restrict__ out) {
  __shared__ __bf16 Alds[BM * BK];   // [m][k] row-major, 8 KB
  __shared__ __bf16 Blds[BN * BK];   // [n][k] row-major, 8 KB
  int t = threadIdx.x;
  int bx = blockIdx.x;
  int nb = bx & 1, mb = bx >> 1;

  // Per-thread staging bases (fixed across K-loop). Each issue covers 64 rows:
  // row = i*64 + t/4, 16B chunk (t&3) within the 64B row.
  size_t baseA[2], baseB[2];
  __bf16 *ldsA[2], *ldsB[2];
  for (int i = 0; i < 2; ++i) {
    int ml = i * 64 + (t >> 2);
    unsigned m = mb * BM + ml;
    unsigned nimg = m / HW;
    unsigned hw = m - nimg * HW;
    unsigned h = hw / WW;
    unsigned w = hw - h * WW;
    baseA[i] = ((size_t)(nimg * HP + h) * HP + w) * CI + (t & 3) * 8;
    baseB[i] = (size_t)(nb * BN + ml) * KTOT + (t & 3) * 8;
    ldsA[i] = &Alds[(size_t)ml * BK + (t & 3) * 8];
    ldsB[i] = &Blds[(size_t)ml * BK + (t & 3) * 8];
  }

  int wid = t >> 6, lane = t & 63;
  int wm = (wid >> 1) * 64, wn = (wid & 1) * 64;   // 64x64 quadrant per wave
  int lr = lane & 15, lk = (lane >> 4) * 8;

  const bf16x8* Af[4];
  const bf16x8* Bf[4];
  for (int i = 0; i < 4; ++i) {
    Af[i] = (const bf16x8*)&Alds[(wm + i * 16 + lr) * BK + lk];
    Bf[i] = (const bf16x8*)&Blds[(wn + i * 16 + lr) * BK + lk];
  }

  f32x4 acc[4][4];
  for (int i = 0; i < 4; ++i)
    for (int j = 0; j < 4; ++j) acc[i][j] = (f32x4){0.f, 0.f, 0.f, 0.f};

  for (int kt = 0; kt < KTOT / BK; ++kt) {
    int rs = kt >> 2;                 // (r,s) fixed per 4 K-chunks (128/32)
    int r = (rs * 11) >> 5;           // rs/3 for rs in [0,9)
    int s = rs - 3 * r;
    size_t offA = ((size_t)(r * HP + s)) * CI + (size_t)(kt & 3) * 32;
    size_t offB = (size_t)kt * BK;
    gload_lds16(xt + baseA[0] + offA, ldsA[0]);
    gload_lds16(xt + baseA[1] + offA, ldsA[1]);
    gload_lds16(wt + baseB[0] + offB, ldsB[0]);
    gload_lds16(wt + baseB[1] + offB, ldsB[1]);
    __syncthreads();                  // drains vmcnt (global_load_lds) + barrier
    bf16x8 a[4], b[4];
    for (int i = 0; i < 4; ++i) { a[i] = *Af[i]; b[i] = *Bf[i]; }
    for (int i = 0; i < 4; ++i)
      for (int j = 0; j < 4; ++j)
        acc[i][j] = __builtin_amdgcn_mfma_f32_16x16x32_bf16(a[i], b[j], acc[i][j], 0, 0, 0);
    __syncthreads();                  // protect LDS before next stage
  }

  // Epilogue: C/D layout col(=n)=lane&15, row(=m)=(lane>>4)*4+reg  [m89-verified]
  for (int j = 0; j < 4; ++j) {
    int o = nb * BN + wn + j * 16 + lr;
    float bv = bias[o];
    for (int i = 0; i < 4; ++i) {
      unsigned m0 = mb * BM + wm + i * 16 + (lane >> 4) * 4;
      for (int r2 = 0; r2 < 4; ++r2) {
        unsigned m = m0 + r2;
        unsigned nimg = m / HW;
        unsigned hw = m - nimg * HW;
        out[((size_t)nimg * CO + o) * HW + hw] = acc[i][j][r2] + bv;
      }
    }
  }
}

extern "C" void kernel_launch(void* const* d_in, const int* in_sizes, int n_in,
                              void* d_out, int out_size, void* d_ws, size_t ws_size,
                              hipStream_t stream) {
  const float* x    = (const float*)d_in[0];
  const float* wg   = (const float*)d_in[1];
  const float* bias = (const float*)d_in[2];
  float* out = (float*)d_out;

  __bf16* xt = (__bf16*)d_ws;
  __bf16* wt = (__bf16*)((char*)d_ws + XT_BYTES);

  int n16 = (int)(XT_BYTES / 16);
  zero_kernel<<<(n16 + 255) / 256, 256, 0, stream>>>((int4*)d_ws, n16);
  xpose_kernel<<<NB * HH, 256, 0, stream>>>(x, xt);
  wxform_kernel<<<(CO * KTOT) / 256, 256, 0, stream>>>(wg, wt);
  conv_gemm<<<(MTOT / BM) * (CO / BN), 256, 0, stream>>>(xt, wt, bias, out);
}

// Round 2
// 225.049 us; speedup vs baseline: 1.0560x; 1.0560x over previous
//
#include <hip/hip_runtime.h>
#include <stdint.h>

typedef __bf16 bf16x8 __attribute__((ext_vector_type(8)));
typedef float  f32x4  __attribute__((ext_vector_type(4)));

#define NB   32
#define CI   128
#define HH   56
#define WW   56
#define CO   256
#define HP   58          // 56 + 2 halo
#define HW   (HH*WW)     // 3136
#define MTOT (NB*HW)     // 100352
#define KTOT 1152        // 9*128, k = (r*3+s)*128 + c

#define XT_ELEMS ((size_t)NB*HP*HP*CI)   // 13,778,944
#define XT_BYTES (XT_ELEMS*2)            // 27,557,888 (16B-aligned)

// ---------- zero only the halo ring of padded x_t (1.87 MB, not 27.5 MB) ----------
// 228 halo pixels per image, each 128 bf16 = 256 B contiguous -> 16 x int4 chunks.
__global__ void halo_zero(__bf16* __restrict__ xt) {
  int id = blockIdx.x * 256 + threadIdx.x;
  if (id >= NB * 228 * 16) return;
  int chunk = id & 15;
  int p = (id >> 4) % 228;
  int n = id / (228 * 16);
  int h, w;
  if (p < 58)       { h = 0;           w = p; }
  else if (p < 116) { h = 57;          w = p - 58; }
  else if (p < 172) { h = p - 116 + 1; w = 0; }
  else              { h = p - 172 + 1; w = 57; }
  int4* dst = (int4*)(xt + ((size_t)(n * HP + h) * HP + w) * CI) + chunk;
  *dst = make_int4(0, 0, 0, 0);
}

// ---------- x: NCHW f32 -> padded NHWC bf16 (LDS transpose per (n,h)) ----------
__global__ void xpose_kernel(const float* __restrict__ x, __bf16* __restrict__ xt) {
  int nh = blockIdx.x;
  int n = nh / HH, h = nh % HH;
  __shared__ float tile[CI][57];       // [c][w], row 57 breaks pow-2 strides
  const float* src = x + (size_t)n * CI * HW + (size_t)h * WW;
  int t = threadIdx.x;
  // load: 14 float4 per c-row, CI rows -> 1792 vec loads, 7 iters
  for (int idx = t; idx < CI * 14; idx += 256) {
    int c = idx / 14, w4 = idx - c * 14;
    float4 v = *(const float4*)(src + (size_t)c * HW + w4 * 4);
    tile[c][w4 * 4 + 0] = v.x;
    tile[c][w4 * 4 + 1] = v.y;
    tile[c][w4 * 4 + 2] = v.z;
    tile[c][w4 * 4 + 3] = v.w;
  }
  __syncthreads();
  __bf16* dst = xt + ((size_t)(n * HP + h + 1) * HP + 1) * CI;
  // store: bf16x8 (16 B) per lane, contiguous in c -> coalesced 256 B/row
  for (int idx = t; idx < WW * 16; idx += 256) {
    int w = idx >> 4, c8 = (idx & 15) * 8;
    bf16x8 v;
    for (int k = 0; k < 8; ++k) v[k] = (__bf16)tile[c8 + k][w];
    *(bf16x8*)(dst + (size_t)w * CI + c8) = v;
  }
}

// ---------- weight: OIHW f32 -> [CO][KTOT] bf16, k=(r*3+s)*128+c ----------
__global__ void wxform_kernel(const float* __restrict__ wg, __bf16* __restrict__ wt) {
  int id = blockIdx.x * 256 + threadIdx.x;   // CO*KTOT = 294912 total
  int o = id / KTOT;
  int k = id - o * KTOT;
  int rs = k >> 7, c = k & 127;
  wt[id] = (__bf16)wg[(size_t)o * KTOT + c * 9 + rs];
}

// ---------- implicit-GEMM conv: m97 structure, BK=64 as two 32-k panels ----------
#define BM 128
#define BN 128

__device__ __forceinline__ void gload_lds16(const __bf16* g, __bf16* l) {
  __builtin_amdgcn_global_load_lds(
      (const __attribute__((address_space(1))) void*)g,
      (__attribute__((address_space(3))) void*)l, 16, 0, 0);
}

__global__ __launch_bounds__(256, 3) void conv_gemm(
    const __bf16* __restrict__ xt, const __bf16* __restrict__ wt,
    const float* __restrict__ bias, float* __restrict__ out) {
  // Two k-panels of 32 each: keeps 64 B LDS row stride (8-way ds_read pattern,
  // same as BK=32) while halving barrier count. 32 KB total -> LDS-limit 5 blk/CU.
  __shared__ __bf16 Alds[2][BM * 32];
  __shared__ __bf16 Blds[2][BN * 32];
  int t = threadIdx.x;
  int bx = blockIdx.x;
  int nb = bx & 1, mb = bx >> 1;

  // Staging: per panel, 2 issues x 256 lanes x 16 B = 8 KB (128 rows x 64 B).
  // LDS dest must be wave-uniform base + lane*16 -> layout is forced contiguous.
  size_t baseA[2], baseB[2];
  __bf16* ldsA[2][2];
  __bf16* ldsB[2][2];
  for (int i = 0; i < 2; ++i) {
    int ml = i * 64 + (t >> 2);
    unsigned m = mb * BM + ml;
    unsigned nimg = m / HW;
    unsigned hw = m - nimg * HW;
    unsigned h = hw / WW;
    unsigned w = hw - h * WW;
    baseA[i] = ((size_t)(nimg * HP + h) * HP + w) * CI + (t & 3) * 8;
    baseB[i] = (size_t)(nb * BN + ml) * KTOT + (t & 3) * 8;
    for (int p = 0; p < 2; ++p) {
      ldsA[i][p] = &Alds[p][ml * 32 + (t & 3) * 8];
      ldsB[i][p] = &Blds[p][ml * 32 + (t & 3) * 8];
    }
  }

  int wid = t >> 6, lane = t & 63;
  int wm = (wid >> 1) * 64, wn = (wid & 1) * 64;   // 64x64 quadrant per wave
  int lr = lane & 15, lk = (lane >> 4) * 8;

  f32x4 acc[4][4];
  for (int i = 0; i < 4; ++i)
    for (int j = 0; j < 4; ++j) acc[i][j] = (f32x4){0.f, 0.f, 0.f, 0.f};

  for (int kt = 0; kt < KTOT / 64; ++kt) {   // 18 iters
    int rs = kt >> 1;                 // (r,s) fixed per 2 K-chunks (128/64)
    int r = (rs * 11) >> 5;           // rs/3 for rs in [0,9)
    int s = rs - 3 * r;
    size_t offA = ((size_t)(r * HP + s)) * CI + (size_t)(kt & 1) * 64;
    size_t offB = (size_t)kt * 64;
    for (int p = 0; p < 2; ++p) {
      gload_lds16(xt + baseA[0] + offA + p * 32, ldsA[0][p]);
      gload_lds16(xt + baseA[1] + offA + p * 32, ldsA[1][p]);
      gload_lds16(wt + baseB[0] + offB + p * 32, ldsB[0][p]);
      gload_lds16(wt + baseB[1] + offB + p * 32, ldsB[1][p]);
    }
    __syncthreads();                  // drains vmcnt (global_load_lds) + barrier
    for (int p = 0; p < 2; ++p) {
      bf16x8 a[4], b[4];
      for (int i = 0; i < 4; ++i) {
        a[i] = *(const bf16x8*)&Alds[p][(wm + i * 16 + lr) * 32 + lk];
        b[i] = *(const bf16x8*)&Blds[p][(wn + i * 16 + lr) * 32 + lk];
      }
      for (int i = 0; i < 4; ++i)
        for (int j = 0; j < 4; ++j)
          acc[i][j] = __builtin_amdgcn_mfma_f32_16x16x32_bf16(a[i], b[j], acc[i][j], 0, 0, 0);
    }
    __syncthreads();                  // protect LDS before next stage
  }

  // Epilogue: C/D layout col(=n)=lane&15, row(=m)=(lane>>4)*4+reg  [m89-verified]
  for (int j = 0; j < 4; ++j) {
    int o = nb * BN + wn + j * 16 + lr;
    float bv = bias[o];
    for (int i = 0; i < 4; ++i) {
      unsigned m0 = mb * BM + wm + i * 16 + (lane >> 4) * 4;
      for (int r2 = 0; r2 < 4; ++r2) {
        unsigned m = m0 + r2;
        unsigned nimg = m / HW;
        unsigned hw = m - nimg * HW;
        out[((size_t)nimg * CO + o) * HW + hw] = acc[i][j][r2] + bv;
      }
    }
  }
}

extern "C" void kernel_launch(void* const* d_in, const int* in_sizes, int n_in,
                              void* d_out, int out_size, void* d_ws, size_t ws_size,
                              hipStream_t stream) {
  const float* x    = (const float*)d_in[0];
  const float* wg   = (const float*)d_in[1];
  const float* bias = (const float*)d_in[2];
  float* out = (float*)d_out;

  __bf16* xt = (__bf16*)d_ws;
  __bf16* wt = (__bf16*)((char*)d_ws + XT_BYTES);

  halo_zero<<<(NB * 228 * 16 + 255) / 256, 256, 0, stream>>>(xt);
  xpose_kernel<<<NB * HH, 256, 0, stream>>>(x, xt);
  wxform_kernel<<<(CO * KTOT) / 256, 256, 0, stream>>>(wg, wt);
  conv_gemm<<<(MTOT / BM) * (CO / BN), 256, 0, stream>>>(xt, wt, bias, out);
}